// Round 10
// baseline (520.094 us; speedup 1.0000x reference)
//
#include <hip/hip_runtime.h>
#include <hip/hip_cooperative_groups.h>
#include <climits>

namespace cg = cooperative_groups;

#define B    8192
#define D    256
#define TOT  16384
#define GS   16
#define NC   (GS * GS * GS)   // 4096 grid cells
#define NCH  32               // rank j-chunks
#define JCW  (TOT / NCH)      // 512
#define RPB  128              // rows per block in norms part
#define NBLK 1024

// ---------------- workspace layout (bytes) ----------------
// sorted_pts4 : f32x4 [B]      @ 0        (131072)
// sorted_idx  : i32  [B]       @ 131072   (32768)
// startg      : i32  [NC+1]    @ 163840   (reserve 32768)
// invn        : f64  [TOT]     @ 196608   (131072)
// S_part      : f64  [128*256] @ 327680   (262144)
// S           : f64  [256]     @ 589824   (2048)
// comb        : f64  [TOT]     @ 591872   (131072)
// partial     : i32  [NCH*TOT] @ 722944   (2097152)
// total ~2.82 MB

__device__ __forceinline__ int clamp_cell(float x) {
    int c = (int)(x * (float)GS);
    if (c < 0) c = 0;
    if (c > GS - 1) c = GS - 1;
    return c;
}

// ONE cooperative kernel, 5 phases separated by grid.sync(). Each phase body
// is the verified round-9 kernel, re-mapped onto 1024 blocks x 256 threads.
__global__ __launch_bounds__(256, 4) void mega(
        const float* __restrict__ mem_tokens, const float* __restrict__ new_tokens,
        const float* __restrict__ ref, const float* __restrict__ mem_keys,
        const float* __restrict__ mem_ages,
        double* __restrict__ invn, double* __restrict__ S_part, double* __restrict__ S,
        double* __restrict__ comb, int* __restrict__ partial,
        float4* __restrict__ sorted_pts4, int* __restrict__ sorted_idx,
        int* __restrict__ startg,
        float* __restrict__ out_keys, float* __restrict__ out_tokens,
        float* __restrict__ out_ages, float* __restrict__ out_closest) {
    cg::grid_group grid = cg::this_grid();
    __shared__ char smem[17408];   // union: P0 norms 8KB | P0 grid 17KB | P3 4KB | P4 128B
    int bid  = blockIdx.x;
    int tid  = threadIdx.x;
    int wave = tid >> 6;
    int lane = tid & 63;

    // ---------- P0: blocks 0..127 norms+spart; block 128 grid build ----------
    if (bid < 128) {
        double (*sacc)[256] = (double(*)[256])smem;
        int rbase = bid * RPB;
        double a0 = 0.0, a1 = 0.0, a2 = 0.0, a3 = 0.0;
        for (int k = wave; k < RPB; k += 4) {
            int r = rbase + k;
            const float* row = (r < B) ? (mem_tokens + (size_t)r * D) : (new_tokens + (size_t)(r - B) * D);
            float4 v = *(const float4*)(row + lane * 4);
            double s = (double)v.x * (double)v.x + (double)v.y * (double)v.y +
                       (double)v.z * (double)v.z + (double)v.w * (double)v.w;
            for (int off = 32; off; off >>= 1) s += __shfl_xor(s, off, 64);
            double n = sqrt(s);
            if (n < 1e-12) n = 1e-12;
            double inv = 1.0 / n;
            if (lane == 0) invn[r] = inv;
            a0 += (double)v.x * inv; a1 += (double)v.y * inv;
            a2 += (double)v.z * inv; a3 += (double)v.w * inv;
        }
        sacc[wave][lane * 4 + 0] = a0;
        sacc[wave][lane * 4 + 1] = a1;
        sacc[wave][lane * 4 + 2] = a2;
        sacc[wave][lane * 4 + 3] = a3;
        __syncthreads();
        S_part[bid * 256 + tid] = sacc[0][tid] + sacc[1][tid] + sacc[2][tid] + sacc[3][tid];
    } else if (bid == 128) {
        int* cnt_s = (int*)smem;            // 16 KB
        int* part  = (int*)(smem + 16384);  // 1 KB
        for (int c = tid; c < NC; c += 256) cnt_s[c] = 0;
        __syncthreads();
        for (int k = 0; k < 32; ++k) {
            int i = k * 256 + tid;
            int cx = clamp_cell(ref[i * 3 + 0]);
            int cy = clamp_cell(ref[i * 3 + 1]);
            int cz = clamp_cell(ref[i * 3 + 2]);
            atomicAdd(&cnt_s[(cz * GS + cy) * GS + cx], 1);
        }
        __syncthreads();
        int s = 0;
        for (int k = 0; k < 16; ++k) s += cnt_s[tid * 16 + k];
        part[tid] = s;
        __syncthreads();
        if (tid == 0) {
            int acc = 0;
            for (int q = 0; q < 256; ++q) { int v = part[q]; part[q] = acc; acc += v; }
        }
        __syncthreads();
        int base = part[tid];
        for (int k = 0; k < 16; ++k) {
            int c = tid * 16 + k;
            int v = cnt_s[c];
            startg[c] = base;
            cnt_s[c] = base;                 // cursor init
            base += v;
        }
        if (tid == 0) startg[NC] = B;
        __syncthreads();
        for (int k = 0; k < 32; ++k) {
            int i = k * 256 + tid;
            float x = ref[i * 3 + 0], y = ref[i * 3 + 1], z = ref[i * 3 + 2];
            int c = (clamp_cell(z) * GS + clamp_cell(y)) * GS + clamp_cell(x);
            float sq = __fadd_rn(__fadd_rn(__fmul_rn(x, x), __fmul_rn(y, y)), __fmul_rn(z, z));
            int pos = atomicAdd(&cnt_s[c], 1);
            sorted_pts4[pos] = make_float4(x, y, z, sq);
            sorted_idx[pos]  = i;
        }
    }
    grid.sync();

    // ---------- P1: all blocks knn (8 queries each); block 0 also s_reduce ----------
    if (bid == 0) {
        double s = 0.0;
        for (int b = 0; b < TOT / RPB; ++b) s += S_part[b * 256 + tid];
        S[tid] = s;
    }
    {
        const float h = 1.0f / (float)GS, eps = 1e-3f;
        for (int qq = 0; qq < 2; ++qq) {
            int k = bid * 8 + qq * 4 + wave;
            float4 q = sorted_pts4[k];
            int i = sorted_idx[k];
            int cx = clamp_cell(q.x), cy = clamp_cell(q.y), cz = clamp_cell(q.z);
            float w0 = INFINITY, w1 = INFINITY, w2 = INFINITY;
            int   wi0 = INT_MAX, wi1 = INT_MAX, wi2 = INT_MAX;
            int R = 0;
            while (true) {
                ++R;
                float b0 = INFINITY, b1 = INFINITY, b2 = INFINITY;
                int   i0 = INT_MAX, i1 = INT_MAX, i2 = INT_MAX;
                int xlo = max(cx - R, 0), xhi = min(cx + R, GS - 1);
                int ylo = max(cy - R, 0), yhi = min(cy + R, GS - 1);
                int zlo = max(cz - R, 0), zhi = min(cz + R, GS - 1);
                int ny = yhi - ylo + 1;
                int rows = ny * (zhi - zlo + 1);
                for (int r = lane; r < rows; r += 64) {
                    int z = zlo + r / ny;
                    int y = ylo + r % ny;
                    int crow = (z * GS + y) * GS;
                    int s = startg[crow + xlo];
                    int e = startg[crow + xhi + 1];
                    for (int t = s; t < e; ++t) {
                        int j = sorted_idx[t];
                        if (j == i) continue;
                        float4 p = sorted_pts4[t];
                        float dot = __fmaf_rn(q.z, p.z, __fmaf_rn(q.y, p.y, __fmul_rn(q.x, p.x)));
                        float d2  = __fsub_rn(__fadd_rn(q.w, p.w), __fmul_rn(2.0f, dot));
                        float d   = __fsqrt_rn(fmaxf(d2, 0.0f));
                        bool lt2 = (d < b2) || (d == b2 && j < i2);
                        if (lt2) {
                            bool lt1 = (d < b1) || (d == b1 && j < i1);
                            if (lt1) {
                                b2 = b1; i2 = i1;
                                bool lt0 = (d < b0) || (d == b0 && j < i0);
                                if (lt0) { b1 = b0; i1 = i0; b0 = d; i0 = j; }
                                else     { b1 = d; i1 = j; }
                            } else { b2 = d; i2 = j; }
                        }
                    }
                }
                #pragma unroll
                for (int s = 0; s < 3; ++s) {
                    float d = b0; int ix = i0;
                    for (int off = 32; off; off >>= 1) {
                        float od = __shfl_xor(d, off, 64);
                        int   oi = __shfl_xor(ix, off, 64);
                        if (od < d || (od == d && oi < ix)) { d = od; ix = oi; }
                    }
                    if (s == 0) { w0 = d; wi0 = ix; }
                    else if (s == 1) { w1 = d; wi1 = ix; }
                    else { w2 = d; wi2 = ix; }
                    if (i0 == ix) { b0 = b1; i0 = i1; b1 = b2; i1 = i2; b2 = INFINITY; i2 = INT_MAX; }
                }
                bool covers = (xlo == 0 && ylo == 0 && zlo == 0 &&
                               xhi == GS - 1 && yhi == GS - 1 && zhi == GS - 1);
                if (covers) break;
                if (wi2 != INT_MAX && w2 < (float)R * h - eps) break;
            }
            if (lane == 0) {
                out_closest[i * 3 + 0] = (float)wi0;
                out_closest[i * 3 + 1] = (float)wi1;
                out_closest[i * 3 + 2] = (float)wi2;
            }
        }
    }
    grid.sync();

    // ---------- P2: combined, 16 rows per block (4 per wave) ----------
    for (int kk = 0; kk < 4; ++kk) {
        int r = bid * 16 + kk * 4 + wave;
        const float* row = (r < B) ? (mem_tokens + (size_t)r * D) : (new_tokens + (size_t)(r - B) * D);
        float4 v = *(const float4*)(row + lane * 4);
        const double* Sp = S + lane * 4;
        double s = (double)v.x * Sp[0] + (double)v.y * Sp[1] +
                   (double)v.z * Sp[2] + (double)v.w * Sp[3];
        for (int off = 32; off; off >>= 1) s += __shfl_down(s, off, 64);
        if (lane == 0) {
            double age = (r < B) ? (double)mem_ages[r] + 1.0 : 0.0;
            comb[r] = age - s * invn[r];
        }
    }
    grid.sync();

    // ---------- P3: rank count (blocks 0..511), verified split-loop ----------
    if (bid < 512) {
        double* cl = (double*)smem;          // 4 KB
        int bx = bid & 15, by = bid >> 4;
        int base = (bx * 256 + tid) * 4;
        int j0   = by * JCW;
        for (int t = tid; t < JCW; t += 256) cl[t] = comb[j0 + t];
        __syncthreads();
        double c0 = comb[base + 0], c1 = comb[base + 1];
        double c2 = comb[base + 2], c3 = comb[base + 3];
        int n0 = 0, n1 = 0, n2 = 0, n3 = 0;
        int lo = base - j0;       if (lo < 0) lo = 0; if (lo > JCW) lo = JCW;
        int hi = base + 4 - j0;   if (hi < 0) hi = 0; if (hi > JCW) hi = JCW;
        #pragma unroll 8
        for (int t = 0; t < lo; ++t) {
            double cj = cl[t];
            n0 += (cj <= c0); n1 += (cj <= c1); n2 += (cj <= c2); n3 += (cj <= c3);
        }
        for (int t = lo; t < hi; ++t) {
            double cj = cl[t];
            int j = j0 + t;
            n0 += (cj < c0) || (cj == c0 && j < base + 0);
            n1 += (cj < c1) || (cj == c1 && j < base + 1);
            n2 += (cj < c2) || (cj == c2 && j < base + 2);
            n3 += (cj < c3) || (cj == c3 && j < base + 3);
        }
        #pragma unroll 8
        for (int t = hi; t < JCW; ++t) {
            double cj = cl[t];
            n0 += (cj < c0); n1 += (cj < c1); n2 += (cj < c2); n3 += (cj < c3);
        }
        *(int4*)&partial[by * TOT + base] = make_int4(n0, n1, n2, n3);
    }
    grid.sync();

    // ---------- P4: gather, 16 rows per block ----------
    {
        int* psum = (int*)smem;
        for (int kk = 0; kk < 16; ++kk) {
            int r = bid * 16 + kk;
            __syncthreads();
            if (tid < 32) psum[tid] = partial[tid * TOT + r];
            __syncthreads();
            if (tid < 8) psum[tid] = psum[tid] + psum[tid + 8] + psum[tid + 16] + psum[tid + 24];
            __syncthreads();
            if (tid == 0) {
                psum[0] = psum[0] + psum[1] + psum[2] + psum[3] +
                          psum[4] + psum[5] + psum[6] + psum[7];
            }
            __syncthreads();
            int rk = psum[0];
            if (rk >= B) continue;
            float4* ot = (float4*)(out_tokens + (size_t)rk * D);
            float4* ok = (float4*)(out_keys + (size_t)rk * 3 * D);
            if (r < B) {
                if (tid < 64) {
                    const float4* st = (const float4*)(mem_tokens + (size_t)r * D);
                    ot[tid] = st[tid];
                } else {
                    const float4* sk = (const float4*)(mem_keys + (size_t)r * 3 * D);
                    ok[tid - 64] = sk[tid - 64];
                }
                if (tid == 0) out_ages[rk] = mem_ages[r] + 1.0f;
            } else {
                const float4* nt = (const float4*)(new_tokens + (size_t)(r - B) * D);
                float4 v = nt[tid & 63];
                if (tid < 64) ot[tid] = v;
                else          ok[tid - 64] = v;
                if (tid == 0) out_ages[rk] = 0.0f;
            }
        }
    }
}

extern "C" void kernel_launch(void* const* d_in, const int* in_sizes, int n_in,
                              void* d_out, int out_size, void* d_ws, size_t ws_size,
                              hipStream_t stream) {
    const float* new_tokens = (const float*)d_in[0];  // [8192,256]
    const float* ref_pts    = (const float*)d_in[1];  // [8192,3]
    const float* mem_keys   = (const float*)d_in[2];  // [8192,3,256]
    const float* mem_tokens = (const float*)d_in[3];  // [8192,256]
    const float* mem_ages   = (const float*)d_in[4];  // [8192]

    char* ws = (char*)d_ws;
    float4* sorted_pts4 = (float4*)(ws + 0);
    int*    sorted_idx  = (int*)   (ws + 131072);
    int*    startg      = (int*)   (ws + 163840);
    double* invn        = (double*)(ws + 196608);
    double* S_part      = (double*)(ws + 327680);
    double* S           = (double*)(ws + 589824);
    double* comb        = (double*)(ws + 591872);
    int*    partial     = (int*)   (ws + 722944);

    float* out = (float*)d_out;
    float* out_keys    = out;                       // 8192*3*256 = 6291456
    float* out_tokens  = out + 6291456;             // 8192*256   = 2097152
    float* out_ages    = out + 6291456 + 2097152;   // 8192
    float* out_closest = out_ages + 8192;           // 8192*3 (written as float)

    void* args[] = {
        (void*)&mem_tokens, (void*)&new_tokens, (void*)&ref_pts, (void*)&mem_keys,
        (void*)&mem_ages,
        (void*)&invn, (void*)&S_part, (void*)&S, (void*)&comb, (void*)&partial,
        (void*)&sorted_pts4, (void*)&sorted_idx, (void*)&startg,
        (void*)&out_keys, (void*)&out_tokens, (void*)&out_ages, (void*)&out_closest
    };
    hipLaunchCooperativeKernel((void*)mega, dim3(NBLK), dim3(256), args, 0, stream);
}

// Round 11
// 125.196 us; speedup vs baseline: 4.1543x; 4.1543x over previous
//
#include <hip/hip_runtime.h>
#include <climits>

#define B    8192
#define D    256
#define TOT  16384
#define GS   16
#define NC   (GS * GS * GS)   // 4096 grid cells
#define NCH  32               // rank j-chunks
#define JCW  (TOT / NCH)      // 512
#define RPB  64               // rows per block in norms part
#define NSB  (TOT / RPB)      // 256 S_part blocks

// ---------------- workspace layout (bytes) ----------------
// sorted_pts4 : f32x4 [B]      @ 0        (131072)
// sorted_idx  : i32  [B]       @ 131072   (32768)
// startg      : i32  [NC+1]    @ 163840   (reserve 32768)
// invn        : f64  [TOT]     @ 196608   (131072)
// S_part      : f64  [256*256] @ 327680   (524288)
// comb        : f64  [TOT]     @ 851968   (131072)
// partial     : i32  [NCH*TOT] @ 983040   (2097152)
// total ~3.08 MB

__device__ __forceinline__ int clamp_cell(float x) {
    int c = (int)(x * (float)GS);
    if (c < 0) c = 0;
    if (c > GS - 1) c = GS - 1;
    return c;
}

// Kernel A: blocks 0..255 -> fused row-norms + partial-S (verified r6/r9, RPB=64);
//           block 256    -> grid build (zero+hist+scan+scatter, 256-thr, verified r8/r9).
__global__ void norms_grid(const float* __restrict__ mem_tokens,
                           const float* __restrict__ new_tokens,
                           const float* __restrict__ ref,
                           double* __restrict__ invn, double* __restrict__ S_part,
                           float4* __restrict__ sorted_pts4, int* __restrict__ sorted_idx,
                           int* __restrict__ startg) {
    __shared__ double sacc[4][256];          // norms branch (8 KB)
    __shared__ int cnt_s[NC];                // grid branch (16 KB)
    __shared__ int part[256];
    if (blockIdx.x < NSB) {
        int wave = threadIdx.x >> 6;
        int lane = threadIdx.x & 63;
        int rbase = blockIdx.x * RPB;
        double a0 = 0.0, a1 = 0.0, a2 = 0.0, a3 = 0.0;
        for (int k = wave; k < RPB; k += 4) {
            int r = rbase + k;
            const float* row = (r < B) ? (mem_tokens + (size_t)r * D) : (new_tokens + (size_t)(r - B) * D);
            float4 v = *(const float4*)(row + lane * 4);
            double s = (double)v.x * (double)v.x + (double)v.y * (double)v.y +
                       (double)v.z * (double)v.z + (double)v.w * (double)v.w;
            for (int off = 32; off; off >>= 1) s += __shfl_xor(s, off, 64);
            double n = sqrt(s);
            if (n < 1e-12) n = 1e-12;
            double inv = 1.0 / n;
            if (lane == 0) invn[r] = inv;
            a0 += (double)v.x * inv; a1 += (double)v.y * inv;
            a2 += (double)v.z * inv; a3 += (double)v.w * inv;
        }
        sacc[wave][lane * 4 + 0] = a0;
        sacc[wave][lane * 4 + 1] = a1;
        sacc[wave][lane * 4 + 2] = a2;
        sacc[wave][lane * 4 + 3] = a3;
        __syncthreads();
        int d = threadIdx.x;
        S_part[blockIdx.x * 256 + d] = sacc[0][d] + sacc[1][d] + sacc[2][d] + sacc[3][d];
    } else {
        int tid = threadIdx.x;
        for (int c = tid; c < NC; c += 256) cnt_s[c] = 0;
        __syncthreads();
        for (int k = 0; k < 32; ++k) {
            int i = k * 256 + tid;
            int cx = clamp_cell(ref[i * 3 + 0]);
            int cy = clamp_cell(ref[i * 3 + 1]);
            int cz = clamp_cell(ref[i * 3 + 2]);
            atomicAdd(&cnt_s[(cz * GS + cy) * GS + cx], 1);
        }
        __syncthreads();
        int s = 0;
        for (int k = 0; k < 16; ++k) s += cnt_s[tid * 16 + k];
        part[tid] = s;
        __syncthreads();
        if (tid == 0) {
            int acc = 0;
            for (int q = 0; q < 256; ++q) { int v = part[q]; part[q] = acc; acc += v; }
        }
        __syncthreads();
        int base = part[tid];
        for (int k = 0; k < 16; ++k) {
            int c = tid * 16 + k;
            int v = cnt_s[c];
            startg[c] = base;
            cnt_s[c] = base;                 // cursor init
            base += v;
        }
        if (tid == 0) startg[NC] = B;
        __syncthreads();
        for (int k = 0; k < 32; ++k) {
            int i = k * 256 + tid;
            float x = ref[i * 3 + 0], y = ref[i * 3 + 1], z = ref[i * 3 + 2];
            int c = (clamp_cell(z) * GS + clamp_cell(y)) * GS + clamp_cell(x);
            float sq = __fadd_rn(__fadd_rn(__fmul_rn(x, x), __fmul_rn(y, y)), __fmul_rn(z, z));
            int pos = atomicAdd(&cnt_s[c], 1);
            sorted_pts4[pos] = make_float4(x, y, z, sq);
            sorted_idx[pos]  = i;
        }
    }
}

// Kernel B: blocks 0..2047  -> wave-per-query grid kNN (verified r5/6/9);
//           blocks 2048..2175 -> combined: per-block S reduce (sequential b order,
//           deterministic) into LDS, then 128 rows of comb (verbatim r9 body).
__global__ void knn_combined(const float4* __restrict__ sorted_pts4,
                             const int* __restrict__ sorted_idx,
                             const int* __restrict__ start,
                             float* __restrict__ out_closest,
                             const float* __restrict__ mem_tokens,
                             const float* __restrict__ new_tokens,
                             const float* __restrict__ mem_ages,
                             const double* __restrict__ invn,
                             const double* __restrict__ S_part,
                             double* __restrict__ comb) {
    __shared__ double Sl[256];
    int wave = threadIdx.x >> 6;
    int lane = threadIdx.x & 63;
    if (blockIdx.x >= 2048) {
        // ---- combined branch ----
        int tid = threadIdx.x;
        double s = 0.0;
        for (int b = 0; b < NSB; ++b) s += S_part[b * 256 + tid];
        Sl[tid] = s;
        __syncthreads();
        int rbase = (blockIdx.x - 2048) * 128;
        for (int k = wave; k < 128; k += 4) {
            int r = rbase + k;
            const float* row = (r < B) ? (mem_tokens + (size_t)r * D) : (new_tokens + (size_t)(r - B) * D);
            float4 v = *(const float4*)(row + lane * 4);
            const double* Sp = Sl + lane * 4;
            double acc = (double)v.x * Sp[0] + (double)v.y * Sp[1] +
                         (double)v.z * Sp[2] + (double)v.w * Sp[3];
            for (int off = 32; off; off >>= 1) acc += __shfl_down(acc, off, 64);
            if (lane == 0) {
                double age = (r < B) ? (double)mem_ages[r] + 1.0 : 0.0;
                comb[r] = age - acc * invn[r];
            }
        }
        return;
    }
    // ---- knn branch ----
    int k = blockIdx.x * 4 + wave;
    float4 q = sorted_pts4[k];
    int i = sorted_idx[k];
    int cx = clamp_cell(q.x), cy = clamp_cell(q.y), cz = clamp_cell(q.z);
    const float h = 1.0f / (float)GS, eps = 1e-3f;
    float w0 = INFINITY, w1 = INFINITY, w2 = INFINITY;
    int   wi0 = INT_MAX, wi1 = INT_MAX, wi2 = INT_MAX;
    int R = 0;
    while (true) {
        ++R;
        float b0 = INFINITY, b1 = INFINITY, b2 = INFINITY;
        int   i0 = INT_MAX, i1 = INT_MAX, i2 = INT_MAX;
        int xlo = max(cx - R, 0), xhi = min(cx + R, GS - 1);
        int ylo = max(cy - R, 0), yhi = min(cy + R, GS - 1);
        int zlo = max(cz - R, 0), zhi = min(cz + R, GS - 1);
        int ny = yhi - ylo + 1;
        int rows = ny * (zhi - zlo + 1);
        for (int r = lane; r < rows; r += 64) {
            int z = zlo + r / ny;
            int y = ylo + r % ny;
            int crow = (z * GS + y) * GS;
            int s = start[crow + xlo];
            int e = start[crow + xhi + 1];
            for (int t = s; t < e; ++t) {
                int j = sorted_idx[t];
                if (j == i) continue;
                float4 p = sorted_pts4[t];
                float dot = __fmaf_rn(q.z, p.z, __fmaf_rn(q.y, p.y, __fmul_rn(q.x, p.x)));
                float d2  = __fsub_rn(__fadd_rn(q.w, p.w), __fmul_rn(2.0f, dot));
                float d   = __fsqrt_rn(fmaxf(d2, 0.0f));
                bool lt2 = (d < b2) || (d == b2 && j < i2);
                if (lt2) {
                    bool lt1 = (d < b1) || (d == b1 && j < i1);
                    if (lt1) {
                        b2 = b1; i2 = i1;
                        bool lt0 = (d < b0) || (d == b0 && j < i0);
                        if (lt0) { b1 = b0; i1 = i0; b0 = d; i0 = j; }
                        else     { b1 = d; i1 = j; }
                    } else { b2 = d; i2 = j; }
                }
            }
        }
        #pragma unroll
        for (int s = 0; s < 3; ++s) {
            float d = b0; int ix = i0;
            for (int off = 32; off; off >>= 1) {
                float od = __shfl_xor(d, off, 64);
                int   oi = __shfl_xor(ix, off, 64);
                if (od < d || (od == d && oi < ix)) { d = od; ix = oi; }
            }
            if (s == 0) { w0 = d; wi0 = ix; }
            else if (s == 1) { w1 = d; wi1 = ix; }
            else { w2 = d; wi2 = ix; }
            if (i0 == ix) { b0 = b1; i0 = i1; b1 = b2; i1 = i2; b2 = INFINITY; i2 = INT_MAX; }
        }
        bool covers = (xlo == 0 && ylo == 0 && zlo == 0 &&
                       xhi == GS - 1 && yhi == GS - 1 && zhi == GS - 1);
        if (covers) break;
        if (wi2 != INT_MAX && w2 < (float)R * h - eps) break;
    }
    if (lane == 0) {
        out_closest[i * 3 + 0] = (float)wi0;
        out_closest[i * 3 + 1] = (float)wi1;
        out_closest[i * 3 + 2] = (float)wi2;
    }
}

// Kernel C: stable rank count (verified r6/r9), NO atomics. 4 consecutive i per
// thread; per-chunk counts -> partial[chunk][i] (int4 store). Split-loop keeps
// the exact lexicographic order; straddle window (<=4 iters) does tie-break.
__global__ void rank_count(const double* __restrict__ comb, int* __restrict__ partial) {
    __shared__ double cl[JCW];
    int tid  = threadIdx.x;
    int base = (blockIdx.x * 256 + tid) * 4;
    int j0   = blockIdx.y * JCW;
    for (int t = tid; t < JCW; t += 256) cl[t] = comb[j0 + t];
    __syncthreads();
    double c0 = comb[base + 0], c1 = comb[base + 1];
    double c2 = comb[base + 2], c3 = comb[base + 3];
    int n0 = 0, n1 = 0, n2 = 0, n3 = 0;
    int lo = base - j0;       if (lo < 0) lo = 0; if (lo > JCW) lo = JCW;
    int hi = base + 4 - j0;   if (hi < 0) hi = 0; if (hi > JCW) hi = JCW;
    #pragma unroll 8
    for (int t = 0; t < lo; ++t) {
        double cj = cl[t];
        n0 += (cj <= c0); n1 += (cj <= c1); n2 += (cj <= c2); n3 += (cj <= c3);
    }
    for (int t = lo; t < hi; ++t) {
        double cj = cl[t];
        int j = j0 + t;
        n0 += (cj < c0) || (cj == c0 && j < base + 0);
        n1 += (cj < c1) || (cj == c1 && j < base + 1);
        n2 += (cj < c2) || (cj == c2 && j < base + 2);
        n3 += (cj < c3) || (cj == c3 && j < base + 3);
    }
    #pragma unroll 8
    for (int t = hi; t < JCW; ++t) {
        double cj = cl[t];
        n0 += (cj < c0); n1 += (cj < c1); n2 += (cj < c2); n3 += (cj < c3);
    }
    *(int4*)&partial[blockIdx.y * TOT + base] = make_int4(n0, n1, n2, n3);
}

// Kernel D: gather (verified r9). Rank reduction ONCE per block: threads 0..31
// load one partial each, LDS tree-reduce, broadcast. float4-vectorized copies.
__global__ void gather(const float* __restrict__ mem_keys, const float* __restrict__ mem_tokens,
                       const float* __restrict__ new_tokens, const float* __restrict__ mem_ages,
                       const int* __restrict__ partial,
                       float* __restrict__ out_keys, float* __restrict__ out_tokens,
                       float* __restrict__ out_ages) {
    __shared__ int psum[32];
    int r = blockIdx.x;
    int t = threadIdx.x;
    if (t < 32) psum[t] = partial[t * TOT + r];
    __syncthreads();
    if (t < 8) {
        int s = psum[t] + psum[t + 8] + psum[t + 16] + psum[t + 24];
        psum[t] = s;
    }
    __syncthreads();
    if (t == 0) {
        psum[0] = psum[0] + psum[1] + psum[2] + psum[3] +
                  psum[4] + psum[5] + psum[6] + psum[7];
    }
    __syncthreads();
    int rk = psum[0];
    if (rk >= B) return;
    float4* ot = (float4*)(out_tokens + (size_t)rk * D);
    float4* ok = (float4*)(out_keys + (size_t)rk * 3 * D);
    if (r < B) {
        if (t < 64) {
            const float4* st = (const float4*)(mem_tokens + (size_t)r * D);
            ot[t] = st[t];
        } else {
            const float4* sk = (const float4*)(mem_keys + (size_t)r * 3 * D);
            ok[t - 64] = sk[t - 64];
        }
        if (t == 0) out_ages[rk] = mem_ages[r] + 1.0f;
    } else {
        const float4* nt = (const float4*)(new_tokens + (size_t)(r - B) * D);
        float4 v = nt[t & 63];
        if (t < 64) ot[t] = v;
        else        ok[t - 64] = v;
        if (t == 0) out_ages[rk] = 0.0f;
    }
}

extern "C" void kernel_launch(void* const* d_in, const int* in_sizes, int n_in,
                              void* d_out, int out_size, void* d_ws, size_t ws_size,
                              hipStream_t stream) {
    const float* new_tokens = (const float*)d_in[0];  // [8192,256]
    const float* ref_pts    = (const float*)d_in[1];  // [8192,3]
    const float* mem_keys   = (const float*)d_in[2];  // [8192,3,256]
    const float* mem_tokens = (const float*)d_in[3];  // [8192,256]
    const float* mem_ages   = (const float*)d_in[4];  // [8192]

    char* ws = (char*)d_ws;
    float4* sorted_pts4 = (float4*)(ws + 0);
    int*    sorted_idx  = (int*)   (ws + 131072);
    int*    startg      = (int*)   (ws + 163840);
    double* invn        = (double*)(ws + 196608);
    double* S_part      = (double*)(ws + 327680);
    double* comb        = (double*)(ws + 851968);
    int*    partial     = (int*)   (ws + 983040);

    float* out = (float*)d_out;
    float* out_keys    = out;                       // 8192*3*256 = 6291456
    float* out_tokens  = out + 6291456;             // 8192*256   = 2097152
    float* out_ages    = out + 6291456 + 2097152;   // 8192
    float* out_closest = out_ages + 8192;           // 8192*3 (written as float)

    norms_grid<<<NSB + 1, 256, 0, stream>>>(mem_tokens, new_tokens, ref_pts,
                                            invn, S_part, sorted_pts4, sorted_idx, startg);
    knn_combined<<<2048 + 128, 256, 0, stream>>>(sorted_pts4, sorted_idx, startg, out_closest,
                                                 mem_tokens, new_tokens, mem_ages, invn,
                                                 S_part, comb);
    rank_count<<<dim3(TOT / (256 * 4), NCH), 256, 0, stream>>>(comb, partial);
    gather<<<TOT, 256, 0, stream>>>(mem_keys, mem_tokens, new_tokens, mem_ages, partial,
                                    out_keys, out_tokens, out_ages);
}

// Round 12
// 97.476 us; speedup vs baseline: 5.3356x; 1.2844x over previous
//
#include <hip/hip_runtime.h>
#include <climits>

#define B    8192
#define D    256
#define TOT  16384
#define GS   16
#define NC   (GS * GS * GS)   // 4096 grid cells
#define NCH  32               // rank j-chunks
#define JCW  (TOT / NCH)      // 512
#define RPB  64               // rows per block in norms part
#define NSB  (TOT / RPB)      // 256 S_part blocks
#define NCB  256              // combined blocks in dispatch 2
#define RCB  (TOT / NCB)      // 64 rows per combined block

// ---------------- workspace layout (bytes) ----------------
// sorted_pts4 : f32x4 [B]      @ 0        (131072)
// sorted_idx  : i32  [B]       @ 131072   (32768)
// startg      : i32  [NC+1]    @ 163840   (reserve 32768)
// invn        : f64  [TOT]     @ 196608   (131072)
// S_part      : f64  [256*256] @ 327680   (524288)
// comb        : f64  [TOT]     @ 851968   (131072)
// partial     : i32  [NCH*TOT] @ 983040   (2097152)
// total ~3.08 MB

__device__ __forceinline__ int clamp_cell(float x) {
    int c = (int)(x * (float)GS);
    if (c < 0) c = 0;
    if (c > GS - 1) c = GS - 1;
    return c;
}

// Kernel A: blocks 0..255 -> fused row-norms + partial-S (verified, RPB=64);
//           block 256    -> grid build with wave-parallel scan (r7 pattern).
__global__ void norms_grid(const float* __restrict__ mem_tokens,
                           const float* __restrict__ new_tokens,
                           const float* __restrict__ ref,
                           double* __restrict__ invn, double* __restrict__ S_part,
                           float4* __restrict__ sorted_pts4, int* __restrict__ sorted_idx,
                           int* __restrict__ startg) {
    __shared__ double sacc[4][256];          // norms branch (8 KB)
    __shared__ int cnt_s[NC];                // grid branch (16 KB)
    __shared__ int wtot[4];
    int wave = threadIdx.x >> 6;
    int lane = threadIdx.x & 63;
    if (blockIdx.x < NSB) {
        int rbase = blockIdx.x * RPB;
        double a0 = 0.0, a1 = 0.0, a2 = 0.0, a3 = 0.0;
        for (int k = wave; k < RPB; k += 4) {
            int r = rbase + k;
            const float* row = (r < B) ? (mem_tokens + (size_t)r * D) : (new_tokens + (size_t)(r - B) * D);
            float4 v = *(const float4*)(row + lane * 4);
            double s = (double)v.x * (double)v.x + (double)v.y * (double)v.y +
                       (double)v.z * (double)v.z + (double)v.w * (double)v.w;
            for (int off = 32; off; off >>= 1) s += __shfl_xor(s, off, 64);
            double n = sqrt(s);
            if (n < 1e-12) n = 1e-12;
            double inv = 1.0 / n;
            if (lane == 0) invn[r] = inv;
            a0 += (double)v.x * inv; a1 += (double)v.y * inv;
            a2 += (double)v.z * inv; a3 += (double)v.w * inv;
        }
        sacc[wave][lane * 4 + 0] = a0;
        sacc[wave][lane * 4 + 1] = a1;
        sacc[wave][lane * 4 + 2] = a2;
        sacc[wave][lane * 4 + 3] = a3;
        __syncthreads();
        int d = threadIdx.x;
        S_part[blockIdx.x * 256 + d] = sacc[0][d] + sacc[1][d] + sacc[2][d] + sacc[3][d];
    } else {
        int tid = threadIdx.x;
        for (int c = tid; c < NC; c += 256) cnt_s[c] = 0;
        __syncthreads();
        for (int k = 0; k < 32; ++k) {
            int i = k * 256 + tid;
            int cx = clamp_cell(ref[i * 3 + 0]);
            int cy = clamp_cell(ref[i * 3 + 1]);
            int cz = clamp_cell(ref[i * 3 + 2]);
            atomicAdd(&cnt_s[(cz * GS + cy) * GS + cx], 1);
        }
        __syncthreads();
        // wave-parallel exclusive scan over 4096 counts (16 cells per thread)
        int n[16]; int s = 0;
        #pragma unroll
        for (int k = 0; k < 16; ++k) { n[k] = cnt_s[tid * 16 + k]; s += n[k]; }
        int incl = s;
        for (int off = 1; off < 64; off <<= 1) {
            int u = __shfl_up(incl, off, 64);
            if (lane >= off) incl += u;
        }
        if (lane == 63) wtot[wave] = incl;
        int excl = incl - s;
        __syncthreads();
        if (tid == 0) {
            int acc = 0;
            for (int w = 0; w < 4; ++w) { int t = wtot[w]; wtot[w] = acc; acc += t; }
        }
        __syncthreads();
        int base = wtot[wave] + excl;
        #pragma unroll
        for (int k = 0; k < 16; ++k) {
            int c = tid * 16 + k;
            startg[c] = base;
            cnt_s[c] = base;                 // cursor init
            base += n[k];
        }
        if (tid == 0) startg[NC] = B;
        __syncthreads();
        for (int k = 0; k < 32; ++k) {
            int i = k * 256 + tid;
            float x = ref[i * 3 + 0], y = ref[i * 3 + 1], z = ref[i * 3 + 2];
            int c = (clamp_cell(z) * GS + clamp_cell(y)) * GS + clamp_cell(x);
            float sq = __fadd_rn(__fadd_rn(__fmul_rn(x, x), __fmul_rn(y, y)), __fmul_rn(z, z));
            int pos = atomicAdd(&cnt_s[c], 1);
            sorted_pts4[pos] = make_float4(x, y, z, sq);
            sorted_idx[pos]  = i;
        }
    }
}

// Kernel B: blocks 0..255   -> combined: 8-accumulator parallel S-reduce into LDS
//                              (fixed tree, deterministic), then 64 rows of comb;
//           blocks 256..2303 -> wave-per-query grid kNN (verified r5/6/9).
__global__ void comb_knn(const float4* __restrict__ sorted_pts4,
                         const int* __restrict__ sorted_idx,
                         const int* __restrict__ start,
                         float* __restrict__ out_closest,
                         const float* __restrict__ mem_tokens,
                         const float* __restrict__ new_tokens,
                         const float* __restrict__ mem_ages,
                         const double* __restrict__ invn,
                         const double* __restrict__ S_part,
                         double* __restrict__ comb) {
    __shared__ double Sl[256];
    int wave = threadIdx.x >> 6;
    int lane = threadIdx.x & 63;
    if (blockIdx.x < NCB) {
        // ---- combined branch (runs first, co-resident with knn) ----
        int tid = threadIdx.x;
        double a0 = 0, a1 = 0, a2 = 0, a3 = 0, a4 = 0, a5 = 0, a6 = 0, a7 = 0;
        for (int b = 0; b < NSB; b += 8) {     // 8 independent load chains
            a0 += S_part[(b + 0) * 256 + tid];
            a1 += S_part[(b + 1) * 256 + tid];
            a2 += S_part[(b + 2) * 256 + tid];
            a3 += S_part[(b + 3) * 256 + tid];
            a4 += S_part[(b + 4) * 256 + tid];
            a5 += S_part[(b + 5) * 256 + tid];
            a6 += S_part[(b + 6) * 256 + tid];
            a7 += S_part[(b + 7) * 256 + tid];
        }
        Sl[tid] = ((a0 + a1) + (a2 + a3)) + ((a4 + a5) + (a6 + a7));
        __syncthreads();
        int rbase = blockIdx.x * RCB;
        for (int k = wave; k < RCB; k += 4) {
            int r = rbase + k;
            const float* row = (r < B) ? (mem_tokens + (size_t)r * D) : (new_tokens + (size_t)(r - B) * D);
            float4 v = *(const float4*)(row + lane * 4);
            const double* Sp = Sl + lane * 4;
            double acc = (double)v.x * Sp[0] + (double)v.y * Sp[1] +
                         (double)v.z * Sp[2] + (double)v.w * Sp[3];
            for (int off = 32; off; off >>= 1) acc += __shfl_down(acc, off, 64);
            if (lane == 0) {
                double age = (r < B) ? (double)mem_ages[r] + 1.0 : 0.0;
                comb[r] = age - acc * invn[r];
            }
        }
        return;
    }
    // ---- knn branch (verbatim verified body) ----
    int k = (blockIdx.x - NCB) * 4 + wave;
    float4 q = sorted_pts4[k];
    int i = sorted_idx[k];
    int cx = clamp_cell(q.x), cy = clamp_cell(q.y), cz = clamp_cell(q.z);
    const float h = 1.0f / (float)GS, eps = 1e-3f;
    float w0 = INFINITY, w1 = INFINITY, w2 = INFINITY;
    int   wi0 = INT_MAX, wi1 = INT_MAX, wi2 = INT_MAX;
    int R = 0;
    while (true) {
        ++R;
        float b0 = INFINITY, b1 = INFINITY, b2 = INFINITY;
        int   i0 = INT_MAX, i1 = INT_MAX, i2 = INT_MAX;
        int xlo = max(cx - R, 0), xhi = min(cx + R, GS - 1);
        int ylo = max(cy - R, 0), yhi = min(cy + R, GS - 1);
        int zlo = max(cz - R, 0), zhi = min(cz + R, GS - 1);
        int ny = yhi - ylo + 1;
        int rows = ny * (zhi - zlo + 1);
        for (int r = lane; r < rows; r += 64) {
            int z = zlo + r / ny;
            int y = ylo + r % ny;
            int crow = (z * GS + y) * GS;
            int s = start[crow + xlo];
            int e = start[crow + xhi + 1];
            for (int t = s; t < e; ++t) {
                int j = sorted_idx[t];
                if (j == i) continue;
                float4 p = sorted_pts4[t];
                float dot = __fmaf_rn(q.z, p.z, __fmaf_rn(q.y, p.y, __fmul_rn(q.x, p.x)));
                float d2  = __fsub_rn(__fadd_rn(q.w, p.w), __fmul_rn(2.0f, dot));
                float d   = __fsqrt_rn(fmaxf(d2, 0.0f));
                bool lt2 = (d < b2) || (d == b2 && j < i2);
                if (lt2) {
                    bool lt1 = (d < b1) || (d == b1 && j < i1);
                    if (lt1) {
                        b2 = b1; i2 = i1;
                        bool lt0 = (d < b0) || (d == b0 && j < i0);
                        if (lt0) { b1 = b0; i1 = i0; b0 = d; i0 = j; }
                        else     { b1 = d; i1 = j; }
                    } else { b2 = d; i2 = j; }
                }
            }
        }
        #pragma unroll
        for (int s = 0; s < 3; ++s) {
            float d = b0; int ix = i0;
            for (int off = 32; off; off >>= 1) {
                float od = __shfl_xor(d, off, 64);
                int   oi = __shfl_xor(ix, off, 64);
                if (od < d || (od == d && oi < ix)) { d = od; ix = oi; }
            }
            if (s == 0) { w0 = d; wi0 = ix; }
            else if (s == 1) { w1 = d; wi1 = ix; }
            else { w2 = d; wi2 = ix; }
            if (i0 == ix) { b0 = b1; i0 = i1; b1 = b2; i1 = i2; b2 = INFINITY; i2 = INT_MAX; }
        }
        bool covers = (xlo == 0 && ylo == 0 && zlo == 0 &&
                       xhi == GS - 1 && yhi == GS - 1 && zhi == GS - 1);
        if (covers) break;
        if (wi2 != INT_MAX && w2 < (float)R * h - eps) break;
    }
    if (lane == 0) {
        out_closest[i * 3 + 0] = (float)wi0;
        out_closest[i * 3 + 1] = (float)wi1;
        out_closest[i * 3 + 2] = (float)wi2;
    }
}

// Kernel C: stable rank count (verified r6/r9), NO atomics. Split-loop keeps
// the exact lexicographic order; straddle window (<=4 iters) does tie-break.
__global__ void rank_count(const double* __restrict__ comb, int* __restrict__ partial) {
    __shared__ double cl[JCW];
    int tid  = threadIdx.x;
    int base = (blockIdx.x * 256 + tid) * 4;
    int j0   = blockIdx.y * JCW;
    for (int t = tid; t < JCW; t += 256) cl[t] = comb[j0 + t];
    __syncthreads();
    double c0 = comb[base + 0], c1 = comb[base + 1];
    double c2 = comb[base + 2], c3 = comb[base + 3];
    int n0 = 0, n1 = 0, n2 = 0, n3 = 0;
    int lo = base - j0;       if (lo < 0) lo = 0; if (lo > JCW) lo = JCW;
    int hi = base + 4 - j0;   if (hi < 0) hi = 0; if (hi > JCW) hi = JCW;
    #pragma unroll 8
    for (int t = 0; t < lo; ++t) {
        double cj = cl[t];
        n0 += (cj <= c0); n1 += (cj <= c1); n2 += (cj <= c2); n3 += (cj <= c3);
    }
    for (int t = lo; t < hi; ++t) {
        double cj = cl[t];
        int j = j0 + t;
        n0 += (cj < c0) || (cj == c0 && j < base + 0);
        n1 += (cj < c1) || (cj == c1 && j < base + 1);
        n2 += (cj < c2) || (cj == c2 && j < base + 2);
        n3 += (cj < c3) || (cj == c3 && j < base + 3);
    }
    #pragma unroll 8
    for (int t = hi; t < JCW; ++t) {
        double cj = cl[t];
        n0 += (cj < c0); n1 += (cj < c1); n2 += (cj < c2); n3 += (cj < c3);
    }
    *(int4*)&partial[blockIdx.y * TOT + base] = make_int4(n0, n1, n2, n3);
}

// Kernel D: gather (verified r9). Rank reduction ONCE per block: threads 0..31
// load one partial each, LDS tree-reduce, broadcast. float4-vectorized copies.
__global__ void gather(const float* __restrict__ mem_keys, const float* __restrict__ mem_tokens,
                       const float* __restrict__ new_tokens, const float* __restrict__ mem_ages,
                       const int* __restrict__ partial,
                       float* __restrict__ out_keys, float* __restrict__ out_tokens,
                       float* __restrict__ out_ages) {
    __shared__ int psum[32];
    int r = blockIdx.x;
    int t = threadIdx.x;
    if (t < 32) psum[t] = partial[t * TOT + r];
    __syncthreads();
    if (t < 8) {
        int s = psum[t] + psum[t + 8] + psum[t + 16] + psum[t + 24];
        psum[t] = s;
    }
    __syncthreads();
    if (t == 0) {
        psum[0] = psum[0] + psum[1] + psum[2] + psum[3] +
                  psum[4] + psum[5] + psum[6] + psum[7];
    }
    __syncthreads();
    int rk = psum[0];
    if (rk >= B) return;
    float4* ot = (float4*)(out_tokens + (size_t)rk * D);
    float4* ok = (float4*)(out_keys + (size_t)rk * 3 * D);
    if (r < B) {
        if (t < 64) {
            const float4* st = (const float4*)(mem_tokens + (size_t)r * D);
            ot[t] = st[t];
        } else {
            const float4* sk = (const float4*)(mem_keys + (size_t)r * 3 * D);
            ok[t - 64] = sk[t - 64];
        }
        if (t == 0) out_ages[rk] = mem_ages[r] + 1.0f;
    } else {
        const float4* nt = (const float4*)(new_tokens + (size_t)(r - B) * D);
        float4 v = nt[t & 63];
        if (t < 64) ot[t] = v;
        else        ok[t - 64] = v;
        if (t == 0) out_ages[rk] = 0.0f;
    }
}

extern "C" void kernel_launch(void* const* d_in, const int* in_sizes, int n_in,
                              void* d_out, int out_size, void* d_ws, size_t ws_size,
                              hipStream_t stream) {
    const float* new_tokens = (const float*)d_in[0];  // [8192,256]
    const float* ref_pts    = (const float*)d_in[1];  // [8192,3]
    const float* mem_keys   = (const float*)d_in[2];  // [8192,3,256]
    const float* mem_tokens = (const float*)d_in[3];  // [8192,256]
    const float* mem_ages   = (const float*)d_in[4];  // [8192]

    char* ws = (char*)d_ws;
    float4* sorted_pts4 = (float4*)(ws + 0);
    int*    sorted_idx  = (int*)   (ws + 131072);
    int*    startg      = (int*)   (ws + 163840);
    double* invn        = (double*)(ws + 196608);
    double* S_part      = (double*)(ws + 327680);
    double* comb        = (double*)(ws + 851968);
    int*    partial     = (int*)   (ws + 983040);

    float* out = (float*)d_out;
    float* out_keys    = out;                       // 8192*3*256 = 6291456
    float* out_tokens  = out + 6291456;             // 8192*256   = 2097152
    float* out_ages    = out + 6291456 + 2097152;   // 8192
    float* out_closest = out_ages + 8192;           // 8192*3 (written as float)

    norms_grid<<<NSB + 1, 256, 0, stream>>>(mem_tokens, new_tokens, ref_pts,
                                            invn, S_part, sorted_pts4, sorted_idx, startg);
    comb_knn<<<NCB + 2048, 256, 0, stream>>>(sorted_pts4, sorted_idx, startg, out_closest,
                                             mem_tokens, new_tokens, mem_ages, invn,
                                             S_part, comb);
    rank_count<<<dim3(TOT / (256 * 4), NCH), 256, 0, stream>>>(comb, partial);
    gather<<<TOT, 256, 0, stream>>>(mem_keys, mem_tokens, new_tokens, mem_ages, partial,
                                    out_keys, out_tokens, out_ages);
}

// Round 13
// 90.416 us; speedup vs baseline: 5.7522x; 1.0781x over previous
//
#include <hip/hip_runtime.h>
#include <climits>

#define B    8192
#define D    256
#define TOT  16384
#define GS   16
#define NC   (GS * GS * GS)   // 4096 grid cells
#define NCH  32               // rank j-chunks
#define JCW  (TOT / NCH)      // 512
#define RPB  64               // rows per block in norms part
#define NSB  (TOT / RPB)      // 256 S_part blocks
#define NCB  256              // combined blocks in dispatch 2
#define RCB  (TOT / NCB)      // 64 rows per combined block

// ---------------- workspace layout (bytes) ----------------
// sorted_pts4 : f32x4 [B]      @ 0        (131072)
// sorted_idx  : i32  [B]       @ 131072   (32768)
// startg      : i32  [NC+1]    @ 163840   (reserve 32768)
// invn        : f64  [TOT]     @ 196608   (131072)
// S_part      : f64  [256*256] @ 327680   (524288)
// comb        : f64  [TOT]     @ 851968   (131072)
// partial     : i32  [NCH*TOT] @ 983040   (2097152)
// total ~3.08 MB

__device__ __forceinline__ int clamp_cell(float x) {
    int c = (int)(x * (float)GS);
    if (c < 0) c = 0;
    if (c > GS - 1) c = GS - 1;
    return c;
}

// Kernel A: blocks 0..255 -> fused row-norms + partial-S (verified, RPB=64);
//           block 256    -> grid build with wave-parallel scan (verified r12).
__global__ void norms_grid(const float* __restrict__ mem_tokens,
                           const float* __restrict__ new_tokens,
                           const float* __restrict__ ref,
                           double* __restrict__ invn, double* __restrict__ S_part,
                           float4* __restrict__ sorted_pts4, int* __restrict__ sorted_idx,
                           int* __restrict__ startg) {
    __shared__ double sacc[4][256];          // norms branch (8 KB)
    __shared__ int cnt_s[NC];                // grid branch (16 KB)
    __shared__ int wtot[4];
    int wave = threadIdx.x >> 6;
    int lane = threadIdx.x & 63;
    if (blockIdx.x < NSB) {
        int rbase = blockIdx.x * RPB;
        double a0 = 0.0, a1 = 0.0, a2 = 0.0, a3 = 0.0;
        for (int k = wave; k < RPB; k += 4) {
            int r = rbase + k;
            const float* row = (r < B) ? (mem_tokens + (size_t)r * D) : (new_tokens + (size_t)(r - B) * D);
            float4 v = *(const float4*)(row + lane * 4);
            double s = (double)v.x * (double)v.x + (double)v.y * (double)v.y +
                       (double)v.z * (double)v.z + (double)v.w * (double)v.w;
            for (int off = 32; off; off >>= 1) s += __shfl_xor(s, off, 64);
            double n = sqrt(s);
            if (n < 1e-12) n = 1e-12;
            double inv = 1.0 / n;
            if (lane == 0) invn[r] = inv;
            a0 += (double)v.x * inv; a1 += (double)v.y * inv;
            a2 += (double)v.z * inv; a3 += (double)v.w * inv;
        }
        sacc[wave][lane * 4 + 0] = a0;
        sacc[wave][lane * 4 + 1] = a1;
        sacc[wave][lane * 4 + 2] = a2;
        sacc[wave][lane * 4 + 3] = a3;
        __syncthreads();
        int d = threadIdx.x;
        S_part[blockIdx.x * 256 + d] = sacc[0][d] + sacc[1][d] + sacc[2][d] + sacc[3][d];
    } else {
        int tid = threadIdx.x;
        for (int c = tid; c < NC; c += 256) cnt_s[c] = 0;
        __syncthreads();
        for (int k = 0; k < 32; ++k) {
            int i = k * 256 + tid;
            int cx = clamp_cell(ref[i * 3 + 0]);
            int cy = clamp_cell(ref[i * 3 + 1]);
            int cz = clamp_cell(ref[i * 3 + 2]);
            atomicAdd(&cnt_s[(cz * GS + cy) * GS + cx], 1);
        }
        __syncthreads();
        int n[16]; int s = 0;
        #pragma unroll
        for (int k = 0; k < 16; ++k) { n[k] = cnt_s[tid * 16 + k]; s += n[k]; }
        int incl = s;
        for (int off = 1; off < 64; off <<= 1) {
            int u = __shfl_up(incl, off, 64);
            if (lane >= off) incl += u;
        }
        if (lane == 63) wtot[wave] = incl;
        int excl = incl - s;
        __syncthreads();
        if (tid == 0) {
            int acc = 0;
            for (int w = 0; w < 4; ++w) { int t = wtot[w]; wtot[w] = acc; acc += t; }
        }
        __syncthreads();
        int base = wtot[wave] + excl;
        #pragma unroll
        for (int k = 0; k < 16; ++k) {
            int c = tid * 16 + k;
            startg[c] = base;
            cnt_s[c] = base;                 // cursor init
            base += n[k];
        }
        if (tid == 0) startg[NC] = B;
        __syncthreads();
        for (int k = 0; k < 32; ++k) {
            int i = k * 256 + tid;
            float x = ref[i * 3 + 0], y = ref[i * 3 + 1], z = ref[i * 3 + 2];
            int c = (clamp_cell(z) * GS + clamp_cell(y)) * GS + clamp_cell(x);
            float sq = __fadd_rn(__fadd_rn(__fmul_rn(x, x), __fmul_rn(y, y)), __fmul_rn(z, z));
            int pos = atomicAdd(&cnt_s[c], 1);
            sorted_pts4[pos] = make_float4(x, y, z, sq);
            sorted_idx[pos]  = i;
        }
    }
}

// Kernel B: blocks 0..255   -> combined (verified r12: 8-acc S-reduce + comb rows);
//           blocks 256..2303 -> grid kNN, wave-per-query with CANDIDATE-level
//           lane parallelism: lane r loads row-span r; shfl_up scan concatenates
//           spans into one candidate space of size M; all 64 lanes process
//           candidates, mapping c->row via 6-step register binary search (shfl).
//           Examined-pair arithmetic and lex (d,idx) selection identical to the
//           verified version => bit-identical output (selection order-invariant).
__global__ void comb_knn(const float4* __restrict__ sorted_pts4,
                         const int* __restrict__ sorted_idx,
                         const int* __restrict__ start,
                         float* __restrict__ out_closest,
                         const float* __restrict__ mem_tokens,
                         const float* __restrict__ new_tokens,
                         const float* __restrict__ mem_ages,
                         const double* __restrict__ invn,
                         const double* __restrict__ S_part,
                         double* __restrict__ comb) {
    __shared__ double Sl[256];
    int wave = threadIdx.x >> 6;
    int lane = threadIdx.x & 63;
    if (blockIdx.x < NCB) {
        // ---- combined branch ----
        int tid = threadIdx.x;
        double a0 = 0, a1 = 0, a2 = 0, a3 = 0, a4 = 0, a5 = 0, a6 = 0, a7 = 0;
        for (int b = 0; b < NSB; b += 8) {     // 8 independent load chains
            a0 += S_part[(b + 0) * 256 + tid];
            a1 += S_part[(b + 1) * 256 + tid];
            a2 += S_part[(b + 2) * 256 + tid];
            a3 += S_part[(b + 3) * 256 + tid];
            a4 += S_part[(b + 4) * 256 + tid];
            a5 += S_part[(b + 5) * 256 + tid];
            a6 += S_part[(b + 6) * 256 + tid];
            a7 += S_part[(b + 7) * 256 + tid];
        }
        Sl[tid] = ((a0 + a1) + (a2 + a3)) + ((a4 + a5) + (a6 + a7));
        __syncthreads();
        int rbase = blockIdx.x * RCB;
        for (int k = wave; k < RCB; k += 4) {
            int r = rbase + k;
            const float* row = (r < B) ? (mem_tokens + (size_t)r * D) : (new_tokens + (size_t)(r - B) * D);
            float4 v = *(const float4*)(row + lane * 4);
            const double* Sp = Sl + lane * 4;
            double acc = (double)v.x * Sp[0] + (double)v.y * Sp[1] +
                         (double)v.z * Sp[2] + (double)v.w * Sp[3];
            for (int off = 32; off; off >>= 1) acc += __shfl_down(acc, off, 64);
            if (lane == 0) {
                double age = (r < B) ? (double)mem_ages[r] + 1.0 : 0.0;
                comb[r] = age - acc * invn[r];
            }
        }
        return;
    }
    // ---- knn branch ----
    int k = (blockIdx.x - NCB) * 4 + wave;
    float4 q = sorted_pts4[k];
    int i = sorted_idx[k];
    int cx = clamp_cell(q.x), cy = clamp_cell(q.y), cz = clamp_cell(q.z);
    const float h = 1.0f / (float)GS, eps = 1e-3f;
    float w0 = INFINITY, w1 = INFINITY, w2 = INFINITY;
    int   wi0 = INT_MAX, wi1 = INT_MAX, wi2 = INT_MAX;
    int R = 0;
    while (true) {
        ++R;
        float b0 = INFINITY, b1 = INFINITY, b2 = INFINITY;
        int   i0 = INT_MAX, i1 = INT_MAX, i2 = INT_MAX;
        int xlo = max(cx - R, 0), xhi = min(cx + R, GS - 1);
        int ylo = max(cy - R, 0), yhi = min(cy + R, GS - 1);
        int zlo = max(cz - R, 0), zhi = min(cz + R, GS - 1);
        int ny = yhi - ylo + 1;
        int rows = ny * (zhi - zlo + 1);
        for (int r0 = 0; r0 < rows; r0 += 64) {
            int r = r0 + lane;
            int sR = 0, cnt = 0;
            if (r < rows) {
                int z = zlo + r / ny;
                int y = ylo + r % ny;
                int crow = (z * GS + y) * GS;
                sR  = start[crow + xlo];
                cnt = start[crow + xhi + 1] - sR;
            }
            // wave exclusive scan of cnt -> excl; M = total candidates this chunk
            int incl = cnt;
            #pragma unroll
            for (int off = 1; off < 64; off <<= 1) {
                int u = __shfl_up(incl, off, 64);
                if (lane >= off) incl += u;
            }
            int excl = incl - cnt;
            int M = __shfl(incl, 63, 64);
            int iters = (M + 63) >> 6;
            for (int it = 0; it < iters; ++it) {
                int c = it * 64 + lane;
                // binary search: largest rsel with excl[rsel] <= c (register shfl)
                int rsel = 0;
                #pragma unroll
                for (int step = 32; step; step >>= 1) {
                    int mid = rsel + step;                 // always <= 63
                    int pm = __shfl(excl, mid, 64);
                    if (pm <= c) rsel = mid;
                }
                int sr = __shfl(sR, rsel, 64);
                int pr = __shfl(excl, rsel, 64);
                if (c < M) {
                    int t = sr + (c - pr);
                    int j = sorted_idx[t];
                    if (j != i) {
                        float4 p = sorted_pts4[t];
                        float dot = __fmaf_rn(q.z, p.z, __fmaf_rn(q.y, p.y, __fmul_rn(q.x, p.x)));
                        float d2  = __fsub_rn(__fadd_rn(q.w, p.w), __fmul_rn(2.0f, dot));
                        float d   = __fsqrt_rn(fmaxf(d2, 0.0f));
                        bool lt2 = (d < b2) || (d == b2 && j < i2);
                        if (lt2) {
                            bool lt1 = (d < b1) || (d == b1 && j < i1);
                            if (lt1) {
                                b2 = b1; i2 = i1;
                                bool lt0 = (d < b0) || (d == b0 && j < i0);
                                if (lt0) { b1 = b0; i1 = i0; b0 = d; i0 = j; }
                                else     { b1 = d; i1 = j; }
                            } else { b2 = d; i2 = j; }
                        }
                    }
                }
            }
        }
        #pragma unroll
        for (int s = 0; s < 3; ++s) {
            float d = b0; int ix = i0;
            for (int off = 32; off; off >>= 1) {
                float od = __shfl_xor(d, off, 64);
                int   oi = __shfl_xor(ix, off, 64);
                if (od < d || (od == d && oi < ix)) { d = od; ix = oi; }
            }
            if (s == 0) { w0 = d; wi0 = ix; }
            else if (s == 1) { w1 = d; wi1 = ix; }
            else { w2 = d; wi2 = ix; }
            if (i0 == ix) { b0 = b1; i0 = i1; b1 = b2; i1 = i2; b2 = INFINITY; i2 = INT_MAX; }
        }
        bool covers = (xlo == 0 && ylo == 0 && zlo == 0 &&
                       xhi == GS - 1 && yhi == GS - 1 && zhi == GS - 1);
        if (covers) break;
        if (wi2 != INT_MAX && w2 < (float)R * h - eps) break;
    }
    if (lane == 0) {
        out_closest[i * 3 + 0] = (float)wi0;
        out_closest[i * 3 + 1] = (float)wi1;
        out_closest[i * 3 + 2] = (float)wi2;
    }
}

// Kernel C: stable rank count (verified r6/r9/r12), NO atomics.
__global__ void rank_count(const double* __restrict__ comb, int* __restrict__ partial) {
    __shared__ double cl[JCW];
    int tid  = threadIdx.x;
    int base = (blockIdx.x * 256 + tid) * 4;
    int j0   = blockIdx.y * JCW;
    for (int t = tid; t < JCW; t += 256) cl[t] = comb[j0 + t];
    __syncthreads();
    double c0 = comb[base + 0], c1 = comb[base + 1];
    double c2 = comb[base + 2], c3 = comb[base + 3];
    int n0 = 0, n1 = 0, n2 = 0, n3 = 0;
    int lo = base - j0;       if (lo < 0) lo = 0; if (lo > JCW) lo = JCW;
    int hi = base + 4 - j0;   if (hi < 0) hi = 0; if (hi > JCW) hi = JCW;
    #pragma unroll 8
    for (int t = 0; t < lo; ++t) {
        double cj = cl[t];
        n0 += (cj <= c0); n1 += (cj <= c1); n2 += (cj <= c2); n3 += (cj <= c3);
    }
    for (int t = lo; t < hi; ++t) {
        double cj = cl[t];
        int j = j0 + t;
        n0 += (cj < c0) || (cj == c0 && j < base + 0);
        n1 += (cj < c1) || (cj == c1 && j < base + 1);
        n2 += (cj < c2) || (cj == c2 && j < base + 2);
        n3 += (cj < c3) || (cj == c3 && j < base + 3);
    }
    #pragma unroll 8
    for (int t = hi; t < JCW; ++t) {
        double cj = cl[t];
        n0 += (cj < c0); n1 += (cj < c1); n2 += (cj < c2); n3 += (cj < c3);
    }
    *(int4*)&partial[blockIdx.y * TOT + base] = make_int4(n0, n1, n2, n3);
}

// Kernel D: gather (verified r9/r12).
__global__ void gather(const float* __restrict__ mem_keys, const float* __restrict__ mem_tokens,
                       const float* __restrict__ new_tokens, const float* __restrict__ mem_ages,
                       const int* __restrict__ partial,
                       float* __restrict__ out_keys, float* __restrict__ out_tokens,
                       float* __restrict__ out_ages) {
    __shared__ int psum[32];
    int r = blockIdx.x;
    int t = threadIdx.x;
    if (t < 32) psum[t] = partial[t * TOT + r];
    __syncthreads();
    if (t < 8) {
        int s = psum[t] + psum[t + 8] + psum[t + 16] + psum[t + 24];
        psum[t] = s;
    }
    __syncthreads();
    if (t == 0) {
        psum[0] = psum[0] + psum[1] + psum[2] + psum[3] +
                  psum[4] + psum[5] + psum[6] + psum[7];
    }
    __syncthreads();
    int rk = psum[0];
    if (rk >= B) return;
    float4* ot = (float4*)(out_tokens + (size_t)rk * D);
    float4* ok = (float4*)(out_keys + (size_t)rk * 3 * D);
    if (r < B) {
        if (t < 64) {
            const float4* st = (const float4*)(mem_tokens + (size_t)r * D);
            ot[t] = st[t];
        } else {
            const float4* sk = (const float4*)(mem_keys + (size_t)r * 3 * D);
            ok[t - 64] = sk[t - 64];
        }
        if (t == 0) out_ages[rk] = mem_ages[r] + 1.0f;
    } else {
        const float4* nt = (const float4*)(new_tokens + (size_t)(r - B) * D);
        float4 v = nt[t & 63];
        if (t < 64) ot[t] = v;
        else        ok[t - 64] = v;
        if (t == 0) out_ages[rk] = 0.0f;
    }
}

extern "C" void kernel_launch(void* const* d_in, const int* in_sizes, int n_in,
                              void* d_out, int out_size, void* d_ws, size_t ws_size,
                              hipStream_t stream) {
    const float* new_tokens = (const float*)d_in[0];  // [8192,256]
    const float* ref_pts    = (const float*)d_in[1];  // [8192,3]
    const float* mem_keys   = (const float*)d_in[2];  // [8192,3,256]
    const float* mem_tokens = (const float*)d_in[3];  // [8192,256]
    const float* mem_ages   = (const float*)d_in[4];  // [8192]

    char* ws = (char*)d_ws;
    float4* sorted_pts4 = (float4*)(ws + 0);
    int*    sorted_idx  = (int*)   (ws + 131072);
    int*    startg      = (int*)   (ws + 163840);
    double* invn        = (double*)(ws + 196608);
    double* S_part      = (double*)(ws + 327680);
    double* comb        = (double*)(ws + 851968);
    int*    partial     = (int*)   (ws + 983040);

    float* out = (float*)d_out;
    float* out_keys    = out;                       // 8192*3*256 = 6291456
    float* out_tokens  = out + 6291456;             // 8192*256   = 2097152
    float* out_ages    = out + 6291456 + 2097152;   // 8192
    float* out_closest = out_ages + 8192;           // 8192*3 (written as float)

    norms_grid<<<NSB + 1, 256, 0, stream>>>(mem_tokens, new_tokens, ref_pts,
                                            invn, S_part, sorted_pts4, sorted_idx, startg);
    comb_knn<<<NCB + 2048, 256, 0, stream>>>(sorted_pts4, sorted_idx, startg, out_closest,
                                             mem_tokens, new_tokens, mem_ages, invn,
                                             S_part, comb);
    rank_count<<<dim3(TOT / (256 * 4), NCH), 256, 0, stream>>>(comb, partial);
    gather<<<TOT, 256, 0, stream>>>(mem_keys, mem_tokens, new_tokens, mem_ages, partial,
                                    out_keys, out_tokens, out_ages);
}